// Round 1
// baseline (455.063 us; speedup 1.0000x reference)
//
#include <hip/hip_runtime.h>
#include <cstddef>

// DigitCaps dynamic routing, fully fused: u recomputed per routing pass,
// logits never materialized (b2 = u.v1, b3 = u.(v1+v2)).
// B=512, O=10, I=1152, OW=16, S=8, ITER=3.

constexpr int O_   = 10;
constexpr int I_   = 1152;
constexpr int W_   = 16;
constexpr int S_   = 8;
constexpr int BQ   = 2;            // batch items per block
constexpr int NTH  = 512;          // 8 waves
constexpr int NWV  = NTH / 64;
constexpr int SLOTS = NWV * 8;     // 64 i-slots (8 per wave)
constexpr int KSEQ  = I_ / SLOTS;  // 18 sequential i per lane per pass
constexpr int OSTR  = I_ * W_ * S_; // 147456 floats per o-panel of W

// Butterfly sum over 8-lane groups (lane bits 0..2) using DPP (VALU-only).
// Steps: quad xor1 (0xB1), quad xor2 (0x4E); after these all 4 lanes of each
// quad hold the quad sum, so row_half_mirror (0x141) delivers the other
// quad's sum. All lanes end with the full 8-lane sum.
__device__ __forceinline__ float dpp_sum8(float v) {
  int t;
  t = __builtin_amdgcn_update_dpp(0, __float_as_int(v), 0xB1, 0xF, 0xF, true);
  v += __int_as_float(t);
  t = __builtin_amdgcn_update_dpp(0, __float_as_int(v), 0x4E, 0xF, 0xF, true);
  v += __int_as_float(t);
  t = __builtin_amdgcn_update_dpp(0, __float_as_int(v), 0x141, 0xF, 0xF, true);
  v += __int_as_float(t);
  return v;
}

__global__ __launch_bounds__(NTH) void digitcaps_fused(
    const float* __restrict__ xg, const float* __restrict__ Wg,
    float* __restrict__ out) {
  __shared__ float s_buf[NWV][BQ][O_][W_];   // per-wave s partials
  __shared__ float vcur[BQ][O_ * W_];        // v used for agreement (v1, then v1+v2)
  __shared__ float v1s[BQ][O_ * W_];         // saved v1

  const int tid  = threadIdx.x;
  const int blk  = blockIdx.x;
  const int wave = tid >> 6;
  const int lane = tid & 63;
  const int isub = lane >> 3;   // 0..7 : which i within the wave
  const int wg   = lane & 7;    // 0..7 : owns w = 2*wg, 2*wg+1

  const float* xp[BQ];
#pragma unroll
  for (int b = 0; b < BQ; ++b)
    xp[b] = xg + (size_t)(blk * BQ + b) * (I_ * S_);
  const float* wb = Wg + (size_t)(wg * 2) * S_;  // + i*(W_*S_) + o*OSTR

  const int ib = wave * 8 + isub;  // i-slot; i = ib + 64*k

  for (int pass = 0; pass < 3; ++pass) {
    float S[BQ][O_][2];
#pragma unroll
    for (int b = 0; b < BQ; ++b)
#pragma unroll
      for (int o = 0; o < O_; ++o) { S[b][o][0] = 0.f; S[b][o][1] = 0.f; }

    if (pass == 0) {
      // c = 1/10 uniform: s = 0.1 * sum_i u  (scale applied in squash phase)
#pragma unroll 2
      for (int k = 0; k < KSEQ; ++k) {
        const int i = ib + SLOTS * k;
        float xf[BQ][S_];
#pragma unroll
        for (int b = 0; b < BQ; ++b) {
          float4 a = *(const float4*)(xp[b] + i * S_);
          float4 c = *(const float4*)(xp[b] + i * S_ + 4);
          xf[b][0]=a.x; xf[b][1]=a.y; xf[b][2]=a.z; xf[b][3]=a.w;
          xf[b][4]=c.x; xf[b][5]=c.y; xf[b][6]=c.z; xf[b][7]=c.w;
        }
        const float* wi = wb + (size_t)i * (W_ * S_);
#pragma unroll
        for (int o = 0; o < O_; ++o) {
          const float4* w4 = (const float4*)(wi + (size_t)o * OSTR);
          float4 w0 = w4[0], w1 = w4[1], w2 = w4[2], w3 = w4[3];
#pragma unroll
          for (int b = 0; b < BQ; ++b) {
            float u0 = w0.x*xf[b][0] + w0.y*xf[b][1] + w0.z*xf[b][2] + w0.w*xf[b][3]
                     + w1.x*xf[b][4] + w1.y*xf[b][5] + w1.z*xf[b][6] + w1.w*xf[b][7];
            float u1 = w2.x*xf[b][0] + w2.y*xf[b][1] + w2.z*xf[b][2] + w2.w*xf[b][3]
                     + w3.x*xf[b][4] + w3.y*xf[b][5] + w3.z*xf[b][6] + w3.w*xf[b][7];
            S[b][o][0] += u0;
            S[b][o][1] += u1;
          }
        }
      }
    } else {
      // agreement logits: pass1 -> u.v1 ; pass2 -> u.(v1+v2) (vcur holds it)
      float vr[BQ][O_][2];
#pragma unroll
      for (int b = 0; b < BQ; ++b)
#pragma unroll
        for (int o = 0; o < O_; ++o) {
          float2 t = *(const float2*)&vcur[b][o * W_ + wg * 2];
          vr[b][o][0] = t.x; vr[b][o][1] = t.y;
        }
#pragma unroll 2
      for (int k = 0; k < KSEQ; ++k) {
        const int i = ib + SLOTS * k;
        float xf[BQ][S_];
#pragma unroll
        for (int b = 0; b < BQ; ++b) {
          float4 a = *(const float4*)(xp[b] + i * S_);
          float4 c = *(const float4*)(xp[b] + i * S_ + 4);
          xf[b][0]=a.x; xf[b][1]=a.y; xf[b][2]=a.z; xf[b][3]=a.w;
          xf[b][4]=c.x; xf[b][5]=c.y; xf[b][6]=c.z; xf[b][7]=c.w;
        }
        const float* wi = wb + (size_t)i * (W_ * S_);
        float U[BQ][O_][2];
        float bl[BQ][O_];
#pragma unroll
        for (int o = 0; o < O_; ++o) {
          const float4* w4 = (const float4*)(wi + (size_t)o * OSTR);
          float4 w0 = w4[0], w1 = w4[1], w2 = w4[2], w3 = w4[3];
#pragma unroll
          for (int b = 0; b < BQ; ++b) {
            float u0 = w0.x*xf[b][0] + w0.y*xf[b][1] + w0.z*xf[b][2] + w0.w*xf[b][3]
                     + w1.x*xf[b][4] + w1.y*xf[b][5] + w1.z*xf[b][6] + w1.w*xf[b][7];
            float u1 = w2.x*xf[b][0] + w2.y*xf[b][1] + w2.z*xf[b][2] + w2.w*xf[b][3]
                     + w3.x*xf[b][4] + w3.y*xf[b][5] + w3.z*xf[b][6] + w3.w*xf[b][7];
            U[b][o][0] = u0; U[b][o][1] = u1;
            // dot over the 16 w's: per-lane dot2, butterfly over 8 wg lanes
            bl[b][o] = dpp_sum8(u0 * vr[b][o][0] + u1 * vr[b][o][1]);
          }
        }
#pragma unroll
        for (int b = 0; b < BQ; ++b) {
          float m = bl[b][0];
#pragma unroll
          for (int o = 1; o < O_; ++o) m = fmaxf(m, bl[b][o]);
          float e[O_];
          float es = 0.f;
#pragma unroll
          for (int o = 0; o < O_; ++o) { e[o] = __expf(bl[b][o] - m); es += e[o]; }
          const float inv = 1.0f / es;
#pragma unroll
          for (int o = 0; o < O_; ++o) {
            const float c = e[o] * inv;
            S[b][o][0] += c * U[b][o][0];
            S[b][o][1] += c * U[b][o][1];
          }
        }
      }
    }

    // reduce s over the 8 i-sub lanes (lane bits 3,4,5)
#pragma unroll
    for (int b = 0; b < BQ; ++b)
#pragma unroll
      for (int o = 0; o < O_; ++o)
#pragma unroll
        for (int ww = 0; ww < 2; ++ww) {
          float s = S[b][o][ww];
          s += __shfl_xor(s, 8);
          s += __shfl_xor(s, 16);
          s += __shfl_xor(s, 32);
          S[b][o][ww] = s;
        }

    if (isub == 0) {
#pragma unroll
      for (int b = 0; b < BQ; ++b)
#pragma unroll
        for (int o = 0; o < O_; ++o) {
          s_buf[wave][b][o][wg * 2 + 0] = S[b][o][0];
          s_buf[wave][b][o][wg * 2 + 1] = S[b][o][1];
        }
    }
    __syncthreads();

    // cross-wave reduce + squash on 320 threads (waves 0..4 fully active)
    if (tid < BQ * O_ * W_) {
      const int bb = tid / (O_ * W_);
      const int r  = tid % (O_ * W_);   // o*16 + w ; lane&15 == w
      float s = 0.f;
#pragma unroll
      for (int wv = 0; wv < NWV; ++wv) s += s_buf[wv][bb][r >> 4][r & 15];
      if (pass == 0) s *= 0.1f;
      float n2 = s * s;
      n2 += __shfl_xor(n2, 1);
      n2 += __shfl_xor(n2, 2);
      n2 += __shfl_xor(n2, 4);
      n2 += __shfl_xor(n2, 8);
      const float v = s * sqrtf(n2) / (1.0f + n2);  // == (n2/(1+n2))*s/sqrt(n2)
      if (pass == 0)      { vcur[bb][r] = v; v1s[bb][r] = v; }
      else if (pass == 1) { vcur[bb][r] = v1s[bb][r] + v; }  // v1+v2 for pass 2
      else                { out[((size_t)(blk * BQ) + bb) * (O_ * W_) + r] = v; }
    }
    __syncthreads();
  }
}

extern "C" void kernel_launch(void* const* d_in, const int* in_sizes, int n_in,
                              void* d_out, int out_size, void* d_ws, size_t ws_size,
                              hipStream_t stream) {
  const float* x = (const float*)d_in[0];   // [512, 32, 8, 6, 6] == [512, 1152, 8]
  const float* W = (const float*)d_in[1];   // [1, 10, 1152, 16, 8]
  float* out = (float*)d_out;               // [512, 10, 16]
  dim3 grid(512 / BQ);   // 256 blocks, 2 batch items each
  dim3 block(NTH);
  hipLaunchKernelGGL(digitcaps_fused, grid, block, 0, stream, x, W, out);
}

// Round 3
// 195.302 us; speedup vs baseline: 2.3301x; 2.3301x over previous
//
#include <hip/hip_runtime.h>
#include <cstddef>
#include <cstdint>

// RETRY of round-2 kernel (previous bench failed with UnresponsiveContainer
// before execution — no GPU result was obtained; design unchanged).
//
// DigitCaps dynamic routing, fully fused, f16 math via v_dot2_f32_f16.
// B=512, O=10, I=1152, OW=16, S=8, ITER=3.
// Pass structure (b-logits never materialized):
//   pass0: c=0.1 uniform -> s1 = 0.1*sum_i u ; v1
//   pass1: b = u.v1          -> softmax -> s2 ; v2
//   pass2: b = u.(v1+v2)     -> softmax -> s3 ; v3 = out
// u recomputed each pass from f16 W (transposed [i][o][w][s] in d_ws, 2.95 MB,
// L2-resident) and f16 x (staged once in LDS).

typedef _Float16 h2 __attribute__((ext_vector_type(2)));

constexpr int O_ = 10, I_ = 1152, W_ = 16, S_ = 8;
constexpr int BQ = 2;               // batch items per block
constexpr int NTH = 512, NWV = 8;
constexpr int SLOTS = NWV * 4;      // 32 concurrent i (16 lanes per i)
constexpr int KSEQ = I_ / SLOTS;    // 36 sequential i per lane per pass
constexpr int WROW = O_ * W_ * S_;  // 1280 halves per i in transposed W

union U32H2 { uint32_t u; h2 h; };
__device__ __forceinline__ h2 as_h2(uint32_t u) { U32H2 c; c.u = u; return c.h; }
__device__ __forceinline__ uint32_t as_u32(h2 h) { U32H2 c; c.h = h; return c.u; }

// Butterfly sum across the 16 lanes of a DPP row (lane bits 0..3), VALU-only.
__device__ __forceinline__ float dpp_sum16(float v) {
  int t;
  t = __builtin_amdgcn_update_dpp(0, __float_as_int(v), 0xB1, 0xF, 0xF, true);  // quad xor1
  v += __int_as_float(t);
  t = __builtin_amdgcn_update_dpp(0, __float_as_int(v), 0x4E, 0xF, 0xF, true);  // quad xor2
  v += __int_as_float(t);
  t = __builtin_amdgcn_update_dpp(0, __float_as_int(v), 0x141, 0xF, 0xF, true); // row_half_mirror
  v += __int_as_float(t);
  t = __builtin_amdgcn_update_dpp(0, __float_as_int(v), 0x140, 0xF, 0xF, true); // row_mirror
  v += __int_as_float(t);
  return v;
}

// W prep: fp32 [o][i][w][s] -> f16 [i][o][w][s]  (2,949,120 B into d_ws)
constexpr int W4TOT = O_ * I_ * W_ * S_ / 4;  // 368640 float4s
__global__ __launch_bounds__(256) void wprep(const float4* __restrict__ Wg,
                                             uint2* __restrict__ Wt) {
  int idx = blockIdx.x * 256 + threadIdx.x;
  if (idx >= W4TOT) return;
  int w2 = idx & 31;        // which float4 within the (o,i) row of 128 floats
  int oi = idx >> 5;        // o*I_ + i
  int o = oi / I_;
  int i = oi - o * I_;
  float4 v = Wg[idx];
  h2 p0 = {(_Float16)v.x, (_Float16)v.y};
  h2 p1 = {(_Float16)v.z, (_Float16)v.w};
  uint2 pk;
  pk.x = as_u32(p0);
  pk.y = as_u32(p1);
  Wt[(i * O_ + o) * 32 + w2] = pk;
}

__global__ __launch_bounds__(NTH, 2) void digitcaps_fused(
    const float* __restrict__ xg, const _Float16* __restrict__ Wt,
    float* __restrict__ out) {
  __shared__ _Float16 xl[BQ * I_ * S_];      // 36,864 B  (f16 x, whole block)
  __shared__ float s_buf[NWV][BQ][O_][W_];   // 10,240 B
  __shared__ float vcur[BQ][O_ * W_];        // v1, then v1+v2 (agreement vector)
  __shared__ float v1s[BQ][O_ * W_];

  const int tid = threadIdx.x, blk = blockIdx.x;
  const int wave = tid >> 6, lane = tid & 63;
  const int wg = lane & 15;     // w column 0..15 (one per lane)
  const int isub = lane >> 4;   // 0..3 : i within the wave

  // ---- stage x -> f16 LDS (once; reused by all 3 passes) ----
  {
    const float4* xb = (const float4*)(xg + (size_t)blk * (BQ * I_ * S_));
    uint2* xw = (uint2*)xl;
#pragma unroll
    for (int j = 0; j < 9; ++j) {
      int f = j * NTH + tid;            // float4 index, 4608 total
      float4 v = xb[f];
      h2 p0 = {(_Float16)v.x, (_Float16)v.y};
      h2 p1 = {(_Float16)v.z, (_Float16)v.w};
      uint2 pk;
      pk.x = as_u32(p0);
      pk.y = as_u32(p1);
      xw[f] = pk;
    }
  }
  __syncthreads();

  const int ib = wave * 4 + isub;  // i-slot; i = ib + 32*k

  for (int pass = 0; pass < 3; ++pass) {
    float S[BQ][O_];
#pragma unroll
    for (int b = 0; b < BQ; ++b)
#pragma unroll
      for (int o = 0; o < O_; ++o) S[b][o] = 0.f;

    if (pass == 0) {
#pragma unroll 2
      for (int k = 0; k < KSEQ; ++k) {
        const int i = ib + SLOTS * k;
        uint32_t xr[BQ][4];
#pragma unroll
        for (int b = 0; b < BQ; ++b) {
          uint4 t = *(const uint4*)&xl[(b * I_ + i) * S_];
          xr[b][0] = t.x; xr[b][1] = t.y; xr[b][2] = t.z; xr[b][3] = t.w;
        }
        const _Float16* wi = Wt + (size_t)i * WROW + wg * S_;
#pragma unroll
        for (int o = 0; o < O_; ++o) {
          uint4 wv = *(const uint4*)(wi + o * (W_ * S_));
#pragma unroll
          for (int b = 0; b < BQ; ++b) {
            float u = __builtin_amdgcn_fdot2(as_h2(wv.x), as_h2(xr[b][0]),
                       __builtin_amdgcn_fdot2(as_h2(wv.y), as_h2(xr[b][1]),
                        __builtin_amdgcn_fdot2(as_h2(wv.z), as_h2(xr[b][2]),
                         __builtin_amdgcn_fdot2(as_h2(wv.w), as_h2(xr[b][3]),
                                                0.f, false), false), false), false);
            S[b][o] += u;
          }
        }
      }
    } else {
      // per-lane v slice for agreement dot: vr[b][o] = vcur[b][o*16 + wg]
      float vr[BQ][O_];
#pragma unroll
      for (int b = 0; b < BQ; ++b)
#pragma unroll
        for (int o = 0; o < O_; ++o) vr[b][o] = vcur[b][o * W_ + wg];

#pragma unroll 2
      for (int k = 0; k < KSEQ; ++k) {
        const int i = ib + SLOTS * k;
        uint32_t xr[BQ][4];
#pragma unroll
        for (int b = 0; b < BQ; ++b) {
          uint4 t = *(const uint4*)&xl[(b * I_ + i) * S_];
          xr[b][0] = t.x; xr[b][1] = t.y; xr[b][2] = t.z; xr[b][3] = t.w;
        }
        const _Float16* wi = Wt + (size_t)i * WROW + wg * S_;
        float U[BQ][O_];
        float bl[BQ][O_];
#pragma unroll
        for (int o = 0; o < O_; ++o) {
          uint4 wv = *(const uint4*)(wi + o * (W_ * S_));
#pragma unroll
          for (int b = 0; b < BQ; ++b) {
            float u = __builtin_amdgcn_fdot2(as_h2(wv.x), as_h2(xr[b][0]),
                       __builtin_amdgcn_fdot2(as_h2(wv.y), as_h2(xr[b][1]),
                        __builtin_amdgcn_fdot2(as_h2(wv.z), as_h2(xr[b][2]),
                         __builtin_amdgcn_fdot2(as_h2(wv.w), as_h2(xr[b][3]),
                                                0.f, false), false), false), false);
            U[b][o] = u;
            bl[b][o] = dpp_sum16(u * vr[b][o]);  // logit: sum over 16 w lanes
          }
        }
#pragma unroll
        for (int b = 0; b < BQ; ++b) {
          float m = bl[b][0];
#pragma unroll
          for (int o = 1; o < O_; ++o) m = fmaxf(m, bl[b][o]);
          float es = 0.f;
#pragma unroll
          for (int o = 0; o < O_; ++o) { bl[b][o] = __expf(bl[b][o] - m); es += bl[b][o]; }
          const float inv = 1.0f / es;
#pragma unroll
          for (int o = 0; o < O_; ++o) S[b][o] += (bl[b][o] * inv) * U[b][o];
        }
      }
    }

    // reduce s over the 4 i-sub lane groups (lane bits 4,5)
#pragma unroll
    for (int b = 0; b < BQ; ++b)
#pragma unroll
      for (int o = 0; o < O_; ++o) {
        float s = S[b][o];
        s += __shfl_xor(s, 16);
        s += __shfl_xor(s, 32);
        S[b][o] = s;
      }
    if (isub == 0) {
#pragma unroll
      for (int b = 0; b < BQ; ++b)
#pragma unroll
        for (int o = 0; o < O_; ++o) s_buf[wave][b][o][wg] = S[b][o];
    }
    __syncthreads();

    // cross-wave reduce + squash on 320 threads
    if (tid < BQ * O_ * W_) {
      const int bb = tid / (O_ * W_);
      const int r = tid % (O_ * W_);  // o*16 + w ; (tid&15)==w
      float s = 0.f;
#pragma unroll
      for (int wv = 0; wv < NWV; ++wv) s += s_buf[wv][bb][r >> 4][r & 15];
      if (pass == 0) s *= 0.1f;
      float n2 = s * s;
      n2 += __shfl_xor(n2, 1);
      n2 += __shfl_xor(n2, 2);
      n2 += __shfl_xor(n2, 4);
      n2 += __shfl_xor(n2, 8);
      const float v = s * sqrtf(n2) / (1.0f + n2);  // == (n2/(1+n2))*s/sqrt(n2)
      if (pass == 0)      { vcur[bb][r] = v; v1s[bb][r] = v; }
      else if (pass == 1) { vcur[bb][r] = v1s[bb][r] + v; }
      else                { out[((size_t)(blk * BQ) + bb) * (O_ * W_) + r] = v; }
    }
    __syncthreads();
  }
}

extern "C" void kernel_launch(void* const* d_in, const int* in_sizes, int n_in,
                              void* d_out, int out_size, void* d_ws, size_t ws_size,
                              hipStream_t stream) {
  const float* x = (const float*)d_in[0];   // [512, 1152, 8]
  const float* W = (const float*)d_in[1];   // [1, 10, 1152, 16, 8]
  float* out = (float*)d_out;               // [512, 10, 16]
  _Float16* Wt = (_Float16*)d_ws;           // 2,949,120 B f16 transposed W

  hipLaunchKernelGGL(wprep, dim3((W4TOT + 255) / 256), dim3(256), 0, stream,
                     (const float4*)W, (uint2*)Wt);
  hipLaunchKernelGGL(digitcaps_fused, dim3(512 / BQ), dim3(NTH), 0, stream,
                     x, Wt, out);
}

// Round 5
// 156.056 us; speedup vs baseline: 2.9160x; 1.2515x over previous
//
#include <hip/hip_runtime.h>
#include <cstddef>
#include <cstdint>

// RETRY of round-4 kernel (bench infra failed with UnresponsiveContainer
// before execution — no GPU result; design unchanged).
//
// DigitCaps dynamic routing, fully fused, f16 math via v_dot2_f32_f16.
// Round 4 change under test: NTH 512 -> 1024 (16 waves/CU instead of 8) to
// attack the latency-bound 53% VALUBusy / 23% occupancy seen in round 3.
// Grid stays 256 blocks (1/CU) so W's L2 traffic is unchanged; per-lane
// KSEQ halves (36 -> 18).
//
// B=512, O=10, I=1152, OW=16, S=8, ITER=3.
// Pass structure (b-logits never materialized):
//   pass0: c=0.1 uniform -> s1 = 0.1*sum_i u ; v1
//   pass1: b = u.v1          -> softmax -> s2 ; v2
//   pass2: b = u.(v1+v2)     -> softmax -> s3 ; v3 = out
// u recomputed each pass from f16 W (transposed [i][o][w][s] in d_ws, 2.95 MB,
// L2-resident) and f16 x (staged once in LDS).

typedef _Float16 h2 __attribute__((ext_vector_type(2)));

constexpr int O_ = 10, I_ = 1152, W_ = 16, S_ = 8;
constexpr int BQ = 2;               // batch items per block
constexpr int NTH = 1024, NWV = 16;
constexpr int SLOTS = NWV * 4;      // 64 concurrent i (16 lanes per i)
constexpr int KSEQ = I_ / SLOTS;    // 18 sequential i per lane per pass
constexpr int WROW = O_ * W_ * S_;  // 1280 halves per i in transposed W

union U32H2 { uint32_t u; h2 h; };
__device__ __forceinline__ h2 as_h2(uint32_t u) { U32H2 c; c.u = u; return c.h; }
__device__ __forceinline__ uint32_t as_u32(h2 h) { U32H2 c; c.h = h; return c.u; }

// Butterfly sum across the 16 lanes of a DPP row (lane bits 0..3), VALU-only.
__device__ __forceinline__ float dpp_sum16(float v) {
  int t;
  t = __builtin_amdgcn_update_dpp(0, __float_as_int(v), 0xB1, 0xF, 0xF, true);  // quad xor1
  v += __int_as_float(t);
  t = __builtin_amdgcn_update_dpp(0, __float_as_int(v), 0x4E, 0xF, 0xF, true);  // quad xor2
  v += __int_as_float(t);
  t = __builtin_amdgcn_update_dpp(0, __float_as_int(v), 0x141, 0xF, 0xF, true); // row_half_mirror
  v += __int_as_float(t);
  t = __builtin_amdgcn_update_dpp(0, __float_as_int(v), 0x140, 0xF, 0xF, true); // row_mirror
  v += __int_as_float(t);
  return v;
}

// W prep: fp32 [o][i][w][s] -> f16 [i][o][w][s]  (2,949,120 B into d_ws)
constexpr int W4TOT = O_ * I_ * W_ * S_ / 4;  // 368640 float4s
__global__ __launch_bounds__(256) void wprep(const float4* __restrict__ Wg,
                                             uint2* __restrict__ Wt) {
  int idx = blockIdx.x * 256 + threadIdx.x;
  if (idx >= W4TOT) return;
  int w2 = idx & 31;        // which float4 within the (o,i) row of 128 floats
  int oi = idx >> 5;        // o*I_ + i
  int o = oi / I_;
  int i = oi - o * I_;
  float4 v = Wg[idx];
  h2 p0 = {(_Float16)v.x, (_Float16)v.y};
  h2 p1 = {(_Float16)v.z, (_Float16)v.w};
  uint2 pk;
  pk.x = as_u32(p0);
  pk.y = as_u32(p1);
  Wt[(i * O_ + o) * 32 + w2] = pk;
}

__global__ __launch_bounds__(NTH, 1) void digitcaps_fused(
    const float* __restrict__ xg, const _Float16* __restrict__ Wt,
    float* __restrict__ out) {
  __shared__ _Float16 xl[BQ * I_ * S_];      // 36,864 B  (f16 x, whole block)
  __shared__ float s_buf[NWV][BQ][O_][W_];   // 20,480 B
  __shared__ float vcur[BQ][O_ * W_];        // v1, then v1+v2 (agreement vector)
  __shared__ float v1s[BQ][O_ * W_];

  const int tid = threadIdx.x, blk = blockIdx.x;
  const int wave = tid >> 6, lane = tid & 63;
  const int wg = lane & 15;     // w column 0..15 (one per lane)
  const int isub = lane >> 4;   // 0..3 : i within the wave

  // ---- stage x -> f16 LDS (once; reused by all 3 passes) ----
  {
    const float4* xb = (const float4*)(xg + (size_t)blk * (BQ * I_ * S_));
    uint2* xw = (uint2*)xl;
#pragma unroll
    for (int j = 0; j < 5; ++j) {
      int f = j * NTH + tid;            // float4 index, 4608 total
      if (f < BQ * I_ * S_ / 4) {
        float4 v = xb[f];
        h2 p0 = {(_Float16)v.x, (_Float16)v.y};
        h2 p1 = {(_Float16)v.z, (_Float16)v.w};
        uint2 pk;
        pk.x = as_u32(p0);
        pk.y = as_u32(p1);
        xw[f] = pk;
      }
    }
  }
  __syncthreads();

  const int ib = wave * 4 + isub;  // i-slot; i = ib + 64*k

  for (int pass = 0; pass < 3; ++pass) {
    float S[BQ][O_];
#pragma unroll
    for (int b = 0; b < BQ; ++b)
#pragma unroll
      for (int o = 0; o < O_; ++o) S[b][o] = 0.f;

    if (pass == 0) {
#pragma unroll 2
      for (int k = 0; k < KSEQ; ++k) {
        const int i = ib + SLOTS * k;
        uint32_t xr[BQ][4];
#pragma unroll
        for (int b = 0; b < BQ; ++b) {
          uint4 t = *(const uint4*)&xl[(b * I_ + i) * S_];
          xr[b][0] = t.x; xr[b][1] = t.y; xr[b][2] = t.z; xr[b][3] = t.w;
        }
        const _Float16* wi = Wt + (size_t)i * WROW + wg * S_;
#pragma unroll
        for (int o = 0; o < O_; ++o) {
          uint4 wv = *(const uint4*)(wi + o * (W_ * S_));
#pragma unroll
          for (int b = 0; b < BQ; ++b) {
            float u = __builtin_amdgcn_fdot2(as_h2(wv.x), as_h2(xr[b][0]),
                       __builtin_amdgcn_fdot2(as_h2(wv.y), as_h2(xr[b][1]),
                        __builtin_amdgcn_fdot2(as_h2(wv.z), as_h2(xr[b][2]),
                         __builtin_amdgcn_fdot2(as_h2(wv.w), as_h2(xr[b][3]),
                                                0.f, false), false), false), false);
            S[b][o] += u;
          }
        }
      }
    } else {
      // per-lane v slice for agreement dot: vr[b][o] = vcur[b][o*16 + wg]
      float vr[BQ][O_];
#pragma unroll
      for (int b = 0; b < BQ; ++b)
#pragma unroll
        for (int o = 0; o < O_; ++o) vr[b][o] = vcur[b][o * W_ + wg];

#pragma unroll 2
      for (int k = 0; k < KSEQ; ++k) {
        const int i = ib + SLOTS * k;
        uint32_t xr[BQ][4];
#pragma unroll
        for (int b = 0; b < BQ; ++b) {
          uint4 t = *(const uint4*)&xl[(b * I_ + i) * S_];
          xr[b][0] = t.x; xr[b][1] = t.y; xr[b][2] = t.z; xr[b][3] = t.w;
        }
        const _Float16* wi = Wt + (size_t)i * WROW + wg * S_;
        float U[BQ][O_];
        float bl[BQ][O_];
#pragma unroll
        for (int o = 0; o < O_; ++o) {
          uint4 wv = *(const uint4*)(wi + o * (W_ * S_));
#pragma unroll
          for (int b = 0; b < BQ; ++b) {
            float u = __builtin_amdgcn_fdot2(as_h2(wv.x), as_h2(xr[b][0]),
                       __builtin_amdgcn_fdot2(as_h2(wv.y), as_h2(xr[b][1]),
                        __builtin_amdgcn_fdot2(as_h2(wv.z), as_h2(xr[b][2]),
                         __builtin_amdgcn_fdot2(as_h2(wv.w), as_h2(xr[b][3]),
                                                0.f, false), false), false), false);
            U[b][o] = u;
            bl[b][o] = dpp_sum16(u * vr[b][o]);  // logit: sum over 16 w lanes
          }
        }
#pragma unroll
        for (int b = 0; b < BQ; ++b) {
          float m = bl[b][0];
#pragma unroll
          for (int o = 1; o < O_; ++o) m = fmaxf(m, bl[b][o]);
          float es = 0.f;
#pragma unroll
          for (int o = 0; o < O_; ++o) { bl[b][o] = __expf(bl[b][o] - m); es += bl[b][o]; }
          const float inv = 1.0f / es;
#pragma unroll
          for (int o = 0; o < O_; ++o) S[b][o] += (bl[b][o] * inv) * U[b][o];
        }
      }
    }

    // reduce s over the 4 i-sub lane groups (lane bits 4,5)
#pragma unroll
    for (int b = 0; b < BQ; ++b)
#pragma unroll
      for (int o = 0; o < O_; ++o) {
        float s = S[b][o];
        s += __shfl_xor(s, 16);
        s += __shfl_xor(s, 32);
        S[b][o] = s;
      }
    if (isub == 0) {
#pragma unroll
      for (int b = 0; b < BQ; ++b)
#pragma unroll
        for (int o = 0; o < O_; ++o) s_buf[wave][b][o][wg] = S[b][o];
    }
    __syncthreads();

    // cross-wave reduce + squash on 320 threads
    if (tid < BQ * O_ * W_) {
      const int bb = tid / (O_ * W_);
      const int r = tid % (O_ * W_);  // o*16 + w ; (tid&15)==w
      float s = 0.f;
#pragma unroll
      for (int wv = 0; wv < NWV; ++wv) s += s_buf[wv][bb][r >> 4][r & 15];
      if (pass == 0) s *= 0.1f;
      float n2 = s * s;
      n2 += __shfl_xor(n2, 1);
      n2 += __shfl_xor(n2, 2);
      n2 += __shfl_xor(n2, 4);
      n2 += __shfl_xor(n2, 8);
      const float v = s * sqrtf(n2) / (1.0f + n2);  // == (n2/(1+n2))*s/sqrt(n2)
      if (pass == 0)      { vcur[bb][r] = v; v1s[bb][r] = v; }
      else if (pass == 1) { vcur[bb][r] = v1s[bb][r] + v; }
      else                { out[((size_t)(blk * BQ) + bb) * (O_ * W_) + r] = v; }
    }
    __syncthreads();
  }
}

extern "C" void kernel_launch(void* const* d_in, const int* in_sizes, int n_in,
                              void* d_out, int out_size, void* d_ws, size_t ws_size,
                              hipStream_t stream) {
  const float* x = (const float*)d_in[0];   // [512, 1152, 8]
  const float* W = (const float*)d_in[1];   // [1, 10, 1152, 16, 8]
  float* out = (float*)d_out;               // [512, 10, 16]
  _Float16* Wt = (_Float16*)d_ws;           // 2,949,120 B f16 transposed W

  hipLaunchKernelGGL(wprep, dim3((W4TOT + 255) / 256), dim3(256), 0, stream,
                     (const float4*)W, (uint2*)Wt);
  hipLaunchKernelGGL(digitcaps_fused, dim3(512 / BQ), dim3(NTH), 0, stream,
                     x, Wt, out);
}